// Round 3
// baseline (457.314 us; speedup 1.0000x reference)
//
#include <hip/hip_runtime.h>
#include <math.h>

// R7: barrier-free main loop. R6's counters (MfmaUtil 12 / VALU 12 / HBM 11 /
// occ 23) showed pure latency-bound serialization: the compiler's vmcnt(0)
// before each of 64 __syncthreads drained the just-issued x prefetch every
// iteration. Fix: drop LDS staging of x entirely — each wave loads its own
// A-fragments straight from global (same per-lane mapping the LDS path
// produced) and does the bf16 hi/lo split in registers. Zero barriers and
// zero LDS traffic in the K-loop -> compiler software-pipelines freely:
// A double-buffered in registers (issued 1 full iter ahead), W (L2-hot)
// issued ~400cy before use. Costs: 4x redundant conversion (VALU was 12%
// busy) and 4x x re-read from L1/L2 (HBM traffic unchanged), 2x W from L2
// (~1 GB aggregate ~ 29 us, overlapped). Conversion trimmed to trunc-hi +
// RNE-lo (residual absorbed by the xl*Wh term; logit noise ~1e-4).

#define T_TOKENS 16384
#define D_K      4096
#define N_EXP    128
#define TOK_BLK  64
#define NITER    64                 // K-steps of 64

typedef float  f32x4  __attribute__((ext_vector_type(4)));
typedef short  bf16x8 __attribute__((ext_vector_type(8)));
typedef float  fragc  __attribute__((ext_vector_type(4)));

__device__ __forceinline__ unsigned short bf16_rne(float f) {
    unsigned u = __float_as_uint(f);
    u += 0x7FFFu + ((u >> 16) & 1u);          // round-to-nearest-even
    return (unsigned short)(u >> 16);
}
__device__ __forceinline__ float bf16f(unsigned short h) {
    return __uint_as_float(((unsigned)h) << 16);
}

// ---------------------------------------------------------------------------
// prep_w: W [128][4096] f32 -> fragment-linear Wh, Wl bf16 (RNE split).
// Line = (kbG*8 + nt)*64 + lane; lane holds W[nt*16+(l&15)][kbG*32+(l>>4)*8+j].
__global__ __launch_bounds__(256)
void prep_w(const float* __restrict__ W,
            short* __restrict__ wh, short* __restrict__ wl) {
    const int gid = blockIdx.x * 256 + threadIdx.x;   // 0..65535 lines
    const int l   = gid & 63;
    const int ntk = gid >> 6;                         // kbG*8 + nt
    const int e   = ((ntk & 7) << 4) + (l & 15);
    const int k   = ((ntk >> 3) << 5) + ((l >> 4) << 3);
    const float* src = W + (size_t)e * D_K + k;
    const f32x4 v0 = *(const f32x4*)src;
    const f32x4 v1 = *(const f32x4*)(src + 4);
    bf16x8 hv, lv;
#pragma unroll
    for (int j = 0; j < 8; ++j) {
        const float f = (j < 4) ? v0[j] : v1[j - 4];
        const unsigned short hh = bf16_rne(f);
        hv[j] = (short)hh;
        lv[j] = (short)bf16_rne(f - bf16f(hh));
    }
    *(bf16x8*)(wh + (size_t)gid * 8) = hv;
    *(bf16x8*)(wl + (size_t)gid * 8) = lv;
}

// ---------------------------------------------------------------------------
// Fused GEMM + softmax + top-2. 256 blocks x 512 thr (8 waves, 2/SIMD).
// Block: 64 tok x 128 exp. Wave: 32 tok (2 Mtiles, wm) x 32 exp (2 Ntiles, wn).
// LDS used ONLY by the epilogue.
#define LOGSTRIDE 140
#define MERGE_OFF (64 * LOGSTRIDE * 4)            // 35840
#define SMEM_SZ   (MERGE_OFF + 64 * 8 * 9 * 4)    // 54272

__global__ __launch_bounds__(512, 2)
void router_mfma(const float* __restrict__ x,
                 const short* __restrict__ wh,
                 const short* __restrict__ wl,
                 const float* __restrict__ bvec,
                 float* __restrict__ out) {
    __shared__ __align__(16) char smem[SMEM_SZ];

    const int tid  = threadIdx.x;
    const int lane = tid & 63;
    const int w    = tid >> 6;
    const int wm   = w >> 2;          // 0..1 : 32-token half
    const int wn   = w & 3;           // 0..3 : 32-expert quarter
    const int g    = blockIdx.x;

    // A-fragment source rows: lane l covers token (l&15), k = (l>>4)*8 + j
    const float* arow0 = x + (size_t)(g * TOK_BLK + wm * 32 + (lane & 15)) * D_K
                           + ((lane >> 4) << 3);
    const float* arow1 = arow0 + (size_t)16 * D_K;    // second Mtile

    // wave-uniform W bases: line = (kbG*8 + wn*2 + nt)*64 + lane, 8 shorts/line
    const short* base_h = wh + ((size_t)(wn * 2) * 64 + lane) * 8;
    const short* base_l = wl + ((size_t)(wn * 2) * 64 + lane) * 8;

    fragc acc[2][2];
#pragma unroll
    for (int mi = 0; mi < 2; ++mi)
#pragma unroll
        for (int nt = 0; nt < 2; ++nt)
            acc[mi][nt] = (fragc){0.f, 0.f, 0.f, 0.f};

    f32x4 Aa[2][2][2], Ab[2][2][2];   // [mi][kb][half], two K-step buffers

    auto loadA = [&](f32x4 (&A)[2][2][2], int t) {
        const float* p0 = arow0 + (size_t)t * 64;
        const float* p1 = arow1 + (size_t)t * 64;
        A[0][0][0] = *(const f32x4*)(p0);
        A[0][0][1] = *(const f32x4*)(p0 + 4);
        A[0][1][0] = *(const f32x4*)(p0 + 32);
        A[0][1][1] = *(const f32x4*)(p0 + 36);
        A[1][0][0] = *(const f32x4*)(p1);
        A[1][0][1] = *(const f32x4*)(p1 + 4);
        A[1][1][0] = *(const f32x4*)(p1 + 32);
        A[1][1][1] = *(const f32x4*)(p1 + 36);
    };

    auto step = [&](f32x4 (&A)[2][2][2], int t) {
        // W fragments for this K-step (L2-hot), issued first
        bf16x8 bh[2][2], bl[2][2];
#pragma unroll
        for (int kb = 0; kb < 2; ++kb) {
            const size_t kofs = (size_t)(2 * t + kb) * 4096;
#pragma unroll
            for (int nt = 0; nt < 2; ++nt) {
                bh[kb][nt] = *(const bf16x8*)(base_h + kofs + nt * 512);
                bl[kb][nt] = *(const bf16x8*)(base_l + kofs + nt * 512);
            }
        }
        // split A (loaded a full iteration ago) into bf16 hi/lo fragments
        bf16x8 ah[2][2], al[2][2];    // [kb][mi]
#pragma unroll
        for (int kb = 0; kb < 2; ++kb)
#pragma unroll
            for (int mi = 0; mi < 2; ++mi)
#pragma unroll
                for (int j = 0; j < 8; ++j) {
                    const float f = (j < 4) ? A[mi][kb][0][j] : A[mi][kb][1][j - 4];
                    const unsigned u  = __float_as_uint(f);
                    const unsigned hu = u & 0xFFFF0000u;
                    ah[kb][mi][j] = (short)(u >> 16);               // trunc hi
                    al[kb][mi][j] = (short)bf16_rne(f - __uint_as_float(hu));
                }
        // A registers free: issue prefetch for K-step t+2 (covered by MFMAs
        // below + the whole next step)
        if (t + 2 < NITER) loadA(A, t + 2);
        // MFMA phase
#pragma unroll
        for (int kb = 0; kb < 2; ++kb)
#pragma unroll
            for (int mi = 0; mi < 2; ++mi)
#pragma unroll
                for (int nt = 0; nt < 2; ++nt) {
                    acc[mi][nt] = __builtin_amdgcn_mfma_f32_16x16x32_bf16(
                        ah[kb][mi], bh[kb][nt], acc[mi][nt], 0, 0, 0);
                    acc[mi][nt] = __builtin_amdgcn_mfma_f32_16x16x32_bf16(
                        al[kb][mi], bh[kb][nt], acc[mi][nt], 0, 0, 0);
                    acc[mi][nt] = __builtin_amdgcn_mfma_f32_16x16x32_bf16(
                        ah[kb][mi], bl[kb][nt], acc[mi][nt], 0, 0, 0);
                }
    };

    loadA(Aa, 0);
    loadA(Ab, 1);
    for (int t = 0; t < NITER; t += 2) {
        step(Aa, t);
        step(Ab, t + 1);
    }

    // ---- epilogue: logits -> LDS, fused softmax + top-2 + renorm ----
    float* lg = (float*)smem;
#pragma unroll
    for (int mi = 0; mi < 2; ++mi) {
        const int row0 = wm * 32 + mi * 16 + ((lane >> 4) << 2);
#pragma unroll
        for (int nt = 0; nt < 2; ++nt) {
            const int col = wn * 32 + nt * 16 + (lane & 15);
#pragma unroll
            for (int j = 0; j < 4; ++j)
                lg[(row0 + j) * LOGSTRIDE + col] = acc[mi][nt][j];
        }
    }
    __syncthreads();

    // 8 threads per token scan 16 experts each (index-ascending, strict > :
    // first-occurrence tie-break, matching jax top_k)
    const int tok = tid & 63;
    const int q   = tid >> 6;             // wave-uniform segment 0..7
    const float* lrow = lg + tok * LOGSTRIDE + q * 16;
    const float* brow = bvec + q * 16;
    float v1 = -INFINITY, v2 = -INFINITY;
    int   i1 = 0, i2 = 0;
#pragma unroll
    for (int c = 0; c < 16; ++c) {
        const float lv = lrow[c] + brow[c];
        if (lv > v1)      { v2 = v1; i2 = i1; v1 = lv; i1 = c; }
        else if (lv > v2) { v2 = lv; i2 = c; }
    }
    float Z = 0.f;
#pragma unroll
    for (int c = 0; c < 16; ++c) Z += expf(lrow[c] + brow[c] - v1);

    float* mrow = (float*)(smem + MERGE_OFF) + (tok * 8 + q) * 9;
    mrow[0] = v1; mrow[1] = (float)(q * 16 + i1);
    mrow[2] = v2; mrow[3] = (float)(q * 16 + i2);
    mrow[4] = Z;
    __syncthreads();

    if (tid < 64) {
        const float* m0 = (float*)(smem + MERGE_OFF) + tid * 72;
        float V1 = m0[0], I1 = m0[1], V2 = m0[2], I2 = m0[3], Zs = m0[4];
#pragma unroll
        for (int q2 = 1; q2 < 8; ++q2) {
            const float* mq = m0 + q2 * 9;
            const float a1 = mq[0], ai1 = mq[1], a2 = mq[2], ai2 = mq[3], Zq = mq[4];
            const float M  = fmaxf(V1, a1);
            Zs = Zs * expf(V1 - M) + Zq * expf(a1 - M);
            if (a1 > V1)      { V2 = V1; I2 = I1; V1 = a1; I1 = ai1; }
            else if (a1 > V2) { V2 = a1; I2 = ai1; }
            if (a2 > V2)      { V2 = a2; I2 = ai2; }
        }
        const float p1 = 1.0f / Zs;               // exp(V1-V1)/Z
        const float p2 = expf(V2 - V1) / Zs;
        const float s  = p1 + p2 + 1e-8f;
        const int tokG = g * TOK_BLK + tid;
        float2* oidx  = (float2*)out;
        float2* oprob = ((float2*)out) + T_TOKENS;
        oidx[tokG]  = make_float2(I1, I2);
        oprob[tokG] = make_float2(p1 / s, p2 / s);
    }
}

extern "C" void kernel_launch(void* const* d_in, const int* in_sizes, int n_in,
                              void* d_out, int out_size, void* d_ws, size_t ws_size,
                              hipStream_t stream) {
    (void)in_sizes; (void)n_in; (void)out_size; (void)ws_size;
    const float* x = (const float*)d_in[0];
    const float* W = (const float*)d_in[1];
    const float* b = (const float*)d_in[2];
    float* out = (float*)d_out;
    short* wh = (short*)d_ws;                         // 1 MB
    short* wl = (short*)d_ws + (size_t)N_EXP * D_K;   // 1 MB

    prep_w<<<dim3(256), dim3(256), 0, stream>>>(W, wh, wl);
    router_mfma<<<dim3(T_TOKENS / TOK_BLK), dim3(512), 0, stream>>>(x, wh, wl, b, out);
}

// Round 4
// 428.368 us; speedup vs baseline: 1.0676x; 1.0676x over previous
//
#include <hip/hip_runtime.h>
#include <math.h>

// R8: back to R6's LDS-staged MFMA structure; remove its two structural limits.
//  - R6 was latency-bound (Mfma 12 / VALU 12 / HBM 11 / occ 23): __syncthreads
//    emits vmcnt(0) which drains the just-issued x prefetch 64x/block.
//    Replace with raw `s_waitcnt lgkmcnt(0); s_barrier` (reg-staged LDS writes
//    only need lgkm visibility) -> x loads stay in flight across barriers.
//  - vmem retires IN-ORDER per wave (R7 lesson): body order is W-loads first
//    (consumed this iter via counted vmcnt leaving x outstanding), then commit
//    (consumes x issued a full iteration ago), then issue x(t+2).
//  - 2 blocks/CU: 512 blocks x 512 thr (32 tok x 128 exp per block), wave tile
//    32tok x 16exp (each W line read once per block -> W L2 traffic 1 GB).
//    4 waves/SIMD cover residual stalls. LDS 25.7 KB.
// Numerics identical to R6 (same RNE hi/lo split, same K order).

#define T_TOKENS 16384
#define D_K      4096
#define N_EXP    128
#define TOK_BLK  32
#define NITER    64                 // K-steps of 64

typedef float  f32x4  __attribute__((ext_vector_type(4)));
typedef short  bf16x8 __attribute__((ext_vector_type(8)));
typedef float  fragc  __attribute__((ext_vector_type(4)));
typedef unsigned int u32;

__device__ __forceinline__ unsigned short bf16_rne(float f) {
    unsigned u = __float_as_uint(f);
    u += 0x7FFFu + ((u >> 16) & 1u);          // round-to-nearest-even
    return (unsigned short)(u >> 16);
}
__device__ __forceinline__ float bf16f(unsigned short h) {
    return __uint_as_float(((unsigned)h) << 16);
}

// A-fragment LDS offset, XOR-swizzled. Line L = G*64 + l (16 B of 8 bf16).
// Read side (fixed G, l=lane 0..63) is a bijection onto 1 KB -> conflict-free
// ds_read_b128; write side lands <=4-way on b64 (cheap).
__device__ __forceinline__ int a_off(int G, int l) {
    const int L  = G * 64 + l;
    const int sw = ((L >> 3) ^ G) & 7;
    return (L << 4) ^ (sw << 4);
}

// ---------------------------------------------------------------------------
// prep_w: W [128][4096] f32 -> fragment-linear Wh, Wl bf16 (RNE split).
// Line = (kbG*8 + nt)*64 + lane; lane holds W[nt*16+(l&15)][kbG*32+(l>>4)*8+j].
__global__ __launch_bounds__(256)
void prep_w(const float* __restrict__ W,
            short* __restrict__ wh, short* __restrict__ wl) {
    const int gid = blockIdx.x * 256 + threadIdx.x;   // 0..65535 lines
    const int l   = gid & 63;
    const int ntk = gid >> 6;                         // kbG*8 + nt
    const int e   = ((ntk & 7) << 4) + (l & 15);
    const int k   = ((ntk >> 3) << 5) + ((l >> 4) << 3);
    const float* src = W + (size_t)e * D_K + k;
    const f32x4 v0 = *(const f32x4*)src;
    const f32x4 v1 = *(const f32x4*)(src + 4);
    bf16x8 hv, lv;
#pragma unroll
    for (int j = 0; j < 8; ++j) {
        const float f = (j < 4) ? v0[j] : v1[j - 4];
        const unsigned short hh = bf16_rne(f);
        hv[j] = (short)hh;
        lv[j] = (short)bf16_rne(f - bf16f(hh));
    }
    *(bf16x8*)(wh + (size_t)gid * 8) = hv;
    *(bf16x8*)(wl + (size_t)gid * 8) = lv;
}

// ---------------------------------------------------------------------------
// Fused GEMM + softmax + top-2. 512 blocks x 512 thr (8 waves, 2 blocks/CU).
// Block: 32 tok x 128 exp. Wave w (0..7): all 32 tokens x experts w*16..+15.
#define LOGSTRIDE 129
#define MERGE_OFF (TOK_BLK * LOGSTRIDE * 4)             // 16512
#define SMEM_SZ   (MERGE_OFF + TOK_BLK * 8 * 9 * 4)     // 25728 (GEMM: 16384)

__global__ __launch_bounds__(512, 4)
void router_mfma(const float* __restrict__ x,
                 const short* __restrict__ wh,
                 const short* __restrict__ wl,
                 const float* __restrict__ bvec,
                 float* __restrict__ out) {
    __shared__ __align__(16) char smem[SMEM_SZ];

    const int tid  = threadIdx.x;
    const int lane = tid & 63;
    const int w    = tid >> 6;        // expert Ntile 0..7
    const int g    = blockIdx.x;

    // staging: thread covers (s_tok = tid>>4, k-chunk s_k4 = tid&15, 4 floats)
    const int s_tok = tid >> 4;       // 0..31
    const int s_k4  = tid & 15;       // 0..15
    const float* xsrc = x + (size_t)(g * TOK_BLK + s_tok) * D_K + s_k4 * 4;
    const int kb_s  = s_k4 >> 3;
    const int c_s   = s_k4 & 7;
    const int mt_s  = s_tok >> 4;
    const int l_s   = (s_tok & 15) | ((c_s >> 1) << 4);
    const int off_s = a_off(kb_s * 2 + mt_s, l_s) + (c_s & 1) * 8;

    f32x4 ld;
    auto issue = [&](int t) { ld = *(const f32x4*)(xsrc + (size_t)t * 64); };
    auto commit = [&](int bufbase) {
        u32 h[2], lo[2];
#pragma unroll
        for (int p = 0; p < 2; ++p) {
            u32 hw = 0, lw = 0;
#pragma unroll
            for (int j = 0; j < 2; ++j) {
                const float f = ld[p * 2 + j];
                const unsigned short hh = bf16_rne(f);
                const unsigned short ll = bf16_rne(f - bf16f(hh));
                hw |= (u32)hh << (16 * j);
                lw |= (u32)ll << (16 * j);
            }
            h[p] = hw; lo[p] = lw;
        }
        *(uint2*)(smem + bufbase + off_s)        = make_uint2(h[0], h[1]);
        *(uint2*)(smem + bufbase + 4096 + off_s) = make_uint2(lo[0], lo[1]);
    };

    // wave-uniform W bases: line = (kbG*8 + w)*64 + lane, 8 shorts/line
    const short* base_h = wh + ((size_t)w * 64 + lane) * 8;
    const short* base_l = wl + ((size_t)w * 64 + lane) * 8;

    fragc acc0 = (fragc){0.f, 0.f, 0.f, 0.f};
    fragc acc1 = (fragc){0.f, 0.f, 0.f, 0.f};

    issue(0);
    commit(0);            // buf0
    issue(1);
    asm volatile("s_waitcnt lgkmcnt(0)\n\ts_barrier" ::: "memory");

    for (int t = 0; t < NITER; ++t) {
        const int cur = (t & 1) << 13;    // 8 KB per buffer (hi 4K + lo 4K)

        // W fragments for this K-step FIRST (oldest in vmem queue: MFMA's
        // counted vmcnt wait won't drain the x prefetch issued below)
        bf16x8 bh[2], bl[2];
#pragma unroll
        for (int kb = 0; kb < 2; ++kb) {
            const size_t kofs = (size_t)(2 * t + kb) * 4096;
            bh[kb] = *(const bf16x8*)(base_h + kofs);
            bl[kb] = *(const bf16x8*)(base_l + kofs);
        }

        // commit tile t+1 (consumes x issued a full iteration ago), then
        // issue x for t+2 (stays in flight across the raw barrier)
        if (t + 1 < NITER) {
            commit(cur ^ 8192);
            if (t + 2 < NITER) issue(t + 2);
        }

        // A fragments from LDS (conflict-free b128 reads)
        bf16x8 ah[2][2], al[2][2];    // [kb][mi]
#pragma unroll
        for (int kb = 0; kb < 2; ++kb)
#pragma unroll
            for (int mi = 0; mi < 2; ++mi) {
                const int off = a_off(kb * 2 + mi, lane);
                ah[kb][mi] = *(const bf16x8*)(smem + cur + off);
                al[kb][mi] = *(const bf16x8*)(smem + cur + 4096 + off);
            }

#pragma unroll
        for (int kb = 0; kb < 2; ++kb) {
            acc0 = __builtin_amdgcn_mfma_f32_16x16x32_bf16(ah[kb][0], bh[kb], acc0, 0, 0, 0);
            acc0 = __builtin_amdgcn_mfma_f32_16x16x32_bf16(al[kb][0], bh[kb], acc0, 0, 0, 0);
            acc0 = __builtin_amdgcn_mfma_f32_16x16x32_bf16(ah[kb][0], bl[kb], acc0, 0, 0, 0);
            acc1 = __builtin_amdgcn_mfma_f32_16x16x32_bf16(ah[kb][1], bh[kb], acc1, 0, 0, 0);
            acc1 = __builtin_amdgcn_mfma_f32_16x16x32_bf16(al[kb][1], bh[kb], acc1, 0, 0, 0);
            acc1 = __builtin_amdgcn_mfma_f32_16x16x32_bf16(ah[kb][1], bl[kb], acc1, 0, 0, 0);
        }

        // raw barrier: LDS visibility only; x prefetch stays outstanding
        asm volatile("s_waitcnt lgkmcnt(0)\n\ts_barrier" ::: "memory");
    }
    __syncthreads();      // full drain once before aliasing smem as logits

    // ---- epilogue: logits -> LDS, fused softmax + top-2 + renorm ----
    float* lg = (float*)smem;
    {
        const int col = w * 16 + (lane & 15);
        const int r0  = (lane >> 4) << 2;
#pragma unroll
        for (int j = 0; j < 4; ++j) lg[(r0 + j) * LOGSTRIDE + col]      = acc0[j];
#pragma unroll
        for (int j = 0; j < 4; ++j) lg[(16 + r0 + j) * LOGSTRIDE + col] = acc1[j];
    }
    __syncthreads();

    // 8 threads per token scan 16 experts each (index-ascending, strict > :
    // first-occurrence tie-break, matching jax top_k). Waves 4..7 idle.
    float* mg = (float*)(smem + MERGE_OFF);
    if (tid < 256) {
        const int tok = tid & 31;
        const int q   = tid >> 5;         // 0..7
        const float* lrow = lg + tok * LOGSTRIDE + q * 16;
        f32x4 lv4[4], bv4[4];
#pragma unroll
        for (int i = 0; i < 4; ++i) lv4[i] = *(const f32x4*)(lrow + i * 4);
#pragma unroll
        for (int i = 0; i < 4; ++i) bv4[i] = *(const f32x4*)(bvec + q * 16 + i * 4);
        float v1 = -INFINITY, v2 = -INFINITY;
        int   i1 = 0, i2 = 0;
#pragma unroll
        for (int i = 0; i < 4; ++i)
#pragma unroll
            for (int j = 0; j < 4; ++j) {
                const int   c  = i * 4 + j;
                const float lv = lv4[i][j] + bv4[i][j];
                if (lv > v1)      { v2 = v1; i2 = i1; v1 = lv; i1 = c; }
                else if (lv > v2) { v2 = lv; i2 = c; }
            }
        float Z = 0.f;
#pragma unroll
        for (int i = 0; i < 4; ++i)
#pragma unroll
            for (int j = 0; j < 4; ++j)
                Z += expf(lv4[i][j] + bv4[i][j] - v1);

        float* mrow = mg + (tok * 8 + q) * 9;
        mrow[0] = v1; mrow[1] = (float)(q * 16 + i1);
        mrow[2] = v2; mrow[3] = (float)(q * 16 + i2);
        mrow[4] = Z;
    }
    __syncthreads();

    if (tid < TOK_BLK) {
        const float* m0 = mg + tid * 72;
        float V1 = m0[0], I1 = m0[1], V2 = m0[2], I2 = m0[3], Zs = m0[4];
#pragma unroll
        for (int q2 = 1; q2 < 8; ++q2) {
            const float* mq = m0 + q2 * 9;
            const float a1 = mq[0], ai1 = mq[1], a2 = mq[2], ai2 = mq[3], Zq = mq[4];
            const float M  = fmaxf(V1, a1);
            Zs = Zs * expf(V1 - M) + Zq * expf(a1 - M);
            if (a1 > V1)      { V2 = V1; I2 = I1; V1 = a1; I1 = ai1; }
            else if (a1 > V2) { V2 = a1; I2 = ai1; }
            if (a2 > V2)      { V2 = a2; I2 = ai2; }
        }
        const float p1 = 1.0f / Zs;               // exp(V1-V1)/Z
        const float p2 = expf(V2 - V1) / Zs;
        const float s  = p1 + p2 + 1e-8f;
        const int tokG = g * TOK_BLK + tid;
        float2* oidx  = (float2*)out;
        float2* oprob = ((float2*)out) + T_TOKENS;
        oidx[tokG]  = make_float2(I1, I2);
        oprob[tokG] = make_float2(p1 / s, p2 / s);
    }
}

extern "C" void kernel_launch(void* const* d_in, const int* in_sizes, int n_in,
                              void* d_out, int out_size, void* d_ws, size_t ws_size,
                              hipStream_t stream) {
    (void)in_sizes; (void)n_in; (void)out_size; (void)ws_size;
    const float* x = (const float*)d_in[0];
    const float* W = (const float*)d_in[1];
    const float* b = (const float*)d_in[2];
    float* out = (float*)d_out;
    short* wh = (short*)d_ws;                         // 1 MB
    short* wl = (short*)d_ws + (size_t)N_EXP * D_K;   // 1 MB

    prep_w<<<dim3(256), dim3(256), 0, stream>>>(W, wh, wl);
    router_mfma<<<dim3(T_TOKENS / TOK_BLK), dim3(512), 0, stream>>>(x, wh, wl, b, out);
}